// Round 9
// baseline (570.180 us; speedup 1.0000x reference)
//
#include <hip/hip_runtime.h>
#include <stdint.h>

// CenterNet postprocess: y_pred (32, 84, 128, 128) f32 -> (32, 100, 8) f32
//
// Round-9: fuse finalize into pass1 via last-block-done reduction.
//   memset(8KB done counters) -> k_fused.
//   k_fused: grid (160,32) x 256. Each block screens 8192 contiguous floats
//   (8 float4/thread, v >= 3.6 max4 guard, rare 3x3 NMS re-checks, private
//   32-slot cand region, count stored unconditionally). Then threadfence +
//   ticket atomicAdd on the batch's padded done counter; ticket 159's block
//   finalizes that batch inline (prefix counts, gather <=512 keys to LDS,
//   bitonic sort, emit top-100 in exact lax.top_k order), overlapped with
//   remaining pass1 work of other batches. Any block overflow / n outside
//   [100,512] -> exact in-block fallback using GLOBAL scratch (hist + keys),
//   never taken on bench data; LDS stays ~6KB so occupancy is unchanged.

#define NCLS    80
#define NCH     84
#define WD      128
#define HD      128
#define HWD     16384
#define NPB     (NCLS * HWD)    // 1310720 heatmap elements per batch
#define NBINS   4096
#define SKCAP   4096
#define FASTCAP 512             // fast-path sort capacity (n~205 expected)
#define MAXDET  100
#define NBATCH  32
#define STHR    3.6f            // static screen threshold (true p100 ~ 3.79)
#define NBLK    160             // pass1 blocks per batch
#define SLOT    32              // candidate slots per pass1 block

// ws layout (bytes):
#define CNT_OFF    0            // 32*160*4 = 20480 (pad to 32768)
#define DONE_OFF   32768        // 32*64*4 = 8192 (zeroed each call)
#define CAND_OFF   65536        // 32*160*32*8 = 1310720
#define FBHIST_OFF 1376256      // 32*4096*4 = 524288 (fallback only)
#define FBKEYS_OFF 1900544      // 32*4096*8 = 1048576 (fallback only)

__device__ __forceinline__ uint32_t fsort(float f) {
  uint32_t u = __float_as_uint(f);
  return u ^ ((u & 0x80000000u) ? 0xFFFFFFFFu : 0x80000000u);
}
__device__ __forceinline__ float funsort(uint32_t u) {
  uint32_t b = (u & 0x80000000u) ? (u ^ 0x80000000u) : ~u;
  return __uint_as_float(b);
}

// exact 3x3 NMS max-of-neighbors for heatmap element e (within one batch)
__device__ __forceinline__ float nms_nbmax(const float* __restrict__ hmb, int e,
                                           float v) {
  int sp = e & (HWD - 1);
  int h = sp >> 7, w = sp & (WD - 1);
  const float* p = hmb + e;
  float m = v;
  bool wl = (w > 0), wr = (w < WD - 1);
  if (wl) m = fmaxf(m, p[-1]);
  if (wr) m = fmaxf(m, p[1]);
  if (h > 0) {
    m = fmaxf(m, p[-WD]);
    if (wl) m = fmaxf(m, p[-WD - 1]);
    if (wr) m = fmaxf(m, p[-WD + 1]);
  }
  if (h < HD - 1) {
    m = fmaxf(m, p[WD]);
    if (wl) m = fmaxf(m, p[WD - 1]);
    if (wr) m = fmaxf(m, p[WD + 1]);
  }
  return m;
}

__device__ __forceinline__ uint64_t make_key(uint32_t u, int e) {
  int sp = e & (HWD - 1);
  uint32_t fi = (uint32_t)(sp * NCLS + (e >> 14));  // (H,W,C) flat index
  return ((uint64_t)u << 32) | (uint32_t)(~fi);
}

extern "C" __global__ __launch_bounds__(256)
void k_fused(const float* __restrict__ in, uint64_t* __restrict__ cand,
             uint32_t* __restrict__ cnt, uint32_t* __restrict__ done,
             uint32_t* __restrict__ fbhist, uint64_t* __restrict__ fbkeys,
             float* __restrict__ out) {
  __shared__ uint32_t lcnt, sIsLast, flags, sthr_s, lcnt2;
  __shared__ uint64_t lbuf[SLOT];
  __shared__ uint32_t pfx[NBLK + 1];
  __shared__ uint64_t sk[FASTCAP];     // 4 KB fast-path sort buffer
  __shared__ uint32_t scnB[256];       // fallback bin scan

  const int t = threadIdx.x;
  const int b = blockIdx.y;
  const int blk = blockIdx.x;
  const float* hmb = in + (size_t)b * NCH * HWD;

  if (t == 0) lcnt = 0;
  __syncthreads();

  // ---------------- pass 1: streaming screen (round-6 proven) --------------
  const int base = blk * 8192 + t * 4;
  float4 v[8];
#pragma unroll
  for (int it = 0; it < 8; ++it)
    v[it] = *reinterpret_cast<const float4*>(hmb + base + it * 1024);

#pragma unroll
  for (int it = 0; it < 8; ++it) {
    float4 w = v[it];
    float m4 = fmaxf(fmaxf(w.x, w.y), fmaxf(w.z, w.w));
    if (m4 >= STHR) {  // rare: one branch guards the detailed checks
      int r = base + it * 1024;
#define TRY(vi, off)                                                     \
      if (vi >= STHR && vi == nms_nbmax(hmb, r + off, vi)) {             \
        uint32_t pos = atomicAdd(&lcnt, 1u);                             \
        if (pos < SLOT) lbuf[pos] = make_key(fsort(vi), r + off);        \
      }
      TRY(w.x, 0) TRY(w.y, 1) TRY(w.z, 2) TRY(w.w, 3)
#undef TRY
    }
  }
  __syncthreads();

  uint32_t n1 = lcnt;
  uint64_t* cb = cand + ((size_t)b * NBLK + blk) * SLOT;
  uint32_t nn = (n1 < SLOT) ? n1 : SLOT;
  for (uint32_t i = t; i < nn; i += 256) cb[i] = lbuf[i];
  if (t == 0) cnt[(size_t)b * NBLK + blk] = n1;  // raw; >SLOT -> fallback

  // ---------------- last-block-done ticket ---------------------------------
  __threadfence();   // release: make this block's cand/cnt globally visible
  __syncthreads();   // all threads' fences complete before the ticket
  if (t == 0) {
    uint32_t old = atomicAdd(&done[(size_t)b * 64], 1u);
    sIsLast = (old == NBLK - 1) ? 1u : 0u;
  }
  __syncthreads();
  if (!sIsLast) return;
  __threadfence();   // acquire: see all other blocks' cand/cnt
  if (t == 0) done[(size_t)b * 64] = 0;  // reset for the next call

  // ---------------- finalize for batch b (one block, overlapped) -----------
  if (t == 0) { flags = 0; sthr_s = 0; lcnt2 = 0; }
  __syncthreads();

  if (t < NBLK) {
    uint32_t c = cnt[(size_t)b * NBLK + t];
    if (c > SLOT) atomicOr(&flags, 1u);
    pfx[t] = c;
  }
  __syncthreads();
  if (t == 0) {
    uint32_t acc = 0;
    for (int i = 0; i < NBLK; ++i) { uint32_t u = pfx[i]; pfx[i] = acc; acc += u; }
    pfx[NBLK] = acc;
  }
  __syncthreads();

  uint32_t n = pfx[NBLK];
  bool fb = (flags != 0) || (n < MAXDET) || (n > FASTCAP);
  uint64_t* fbk = fbkeys + (size_t)b * SKCAP;

  if (!fb) {
    // gather per-block segments into contiguous sk[0..n)
    const uint64_t* cba = cand + (size_t)b * NBLK * SLOT;
    for (int i = t; i < NBLK; i += 256) {
      uint32_t off = pfx[i], ci = pfx[i + 1] - off;
      for (uint32_t j = 0; j < ci; ++j) sk[off + j] = cba[(size_t)i * SLOT + j];
    }
    __syncthreads();
    uint32_t m = 128; while (m < n) m <<= 1;
    for (uint32_t i = t; i < m; i += 256) if (i >= n) sk[i] = 0ull;
    __syncthreads();
    // bitonic sort desc by (value, ~fi): value desc, index asc on ties
    for (uint32_t k = 2; k <= m; k <<= 1) {
      for (uint32_t j = k >> 1; j > 0; j >>= 1) {
        for (uint32_t i = t; i < m; i += 256) {
          uint32_t ixj = i ^ j;
          if (ixj > i && ixj < m) {
            uint64_t a = sk[i], c = sk[ixj];
            bool desc = (i & k) == 0;
            if (desc ? (a < c) : (a > c)) { sk[i] = c; sk[ixj] = a; }
          }
        }
        __syncthreads();
      }
    }
  } else {
    // ---- exact fallback in GLOBAL scratch (never taken on bench data) -----
    uint32_t* hb = fbhist + (size_t)b * NBINS;
    for (int i = t; i < NBINS; i += 256) hb[i] = 0;
    __syncthreads();
    uint32_t zp = 0, zn = 0;
    for (int e = t; e < NPB; e += 256) {
      float vv = hmb[e];
      if (vv == nms_nbmax(hmb, e, vv)) {
        atomicAdd(&hb[fsort(vv) >> 20], 1u);
      } else if (__float_as_uint(vv) >> 31) zn++; else zp++;
    }
    for (int off = 32; off; off >>= 1) {
      zp += __shfl_down(zp, off);
      zn += __shfl_down(zn, off);
    }
    if ((t & 63) == 0) {
      if (zp) atomicAdd(&hb[2048], zp);  // suppressed +0.0
      if (zn) atomicAdd(&hb[2047], zn);  // suppressed -0.0
    }
    __syncthreads();
    uint32_t loc[16], own = 0;
#pragma unroll
    for (int i = 0; i < 16; ++i) { loc[i] = hb[t * 16 + i]; own += loc[i]; }
    scnB[t] = own;
    __syncthreads();
    if (t == 0) {
      uint32_t acc = 0;
      for (int j = 255; j >= 0; --j) { uint32_t u = scnB[j]; scnB[j] = acc; acc += u; }
    }
    __syncthreads();
    uint32_t above = scnB[t];
    if (above < MAXDET && above + own >= MAXDET) {
      uint32_t cum = above;
      for (int i = 15; i >= 0; --i) {
        cum += loc[i];
        if (cum >= MAXDET) { sthr_s = (uint32_t)(t * 16 + i); break; }
      }
    }
    __syncthreads();
    uint32_t uthr = sthr_s << 20;
    for (int e = t; e < NPB; e += 256) {
      float vv = hmb[e];
      bool kept = (vv == nms_nbmax(hmb, e, vv));
      float nv = kept ? vv : 0.0f * vv;
      uint32_t u = fsort(nv);
      if (u >= uthr) {
        uint32_t pos = atomicAdd(&lcnt2, 1u);
        if (pos < SKCAP) fbk[pos] = make_key(u, e);
      }
    }
    __syncthreads();
    n = lcnt2; if (n > SKCAP) n = SKCAP;
    uint32_t m = 128; while (m < n) m <<= 1;
    for (uint32_t i = t; i < m; i += 256) if (i >= n) fbk[i] = 0ull;
    __syncthreads();
    for (uint32_t k = 2; k <= m; k <<= 1) {
      for (uint32_t j = k >> 1; j > 0; j >>= 1) {
        for (uint32_t i = t; i < m; i += 256) {
          uint32_t ixj = i ^ j;
          if (ixj > i && ixj < m) {
            uint64_t a = fbk[i], c = fbk[ixj];
            bool desc = (i & k) == 0;
            if (desc ? (a < c) : (a > c)) { fbk[i] = c; fbk[ixj] = a; }
          }
        }
        __syncthreads();
      }
    }
  }

  // ---------------- emit top-100 -------------------------------------------
  if (t < MAXDET) {
    uint64_t key = fb ? fbk[t] : sk[t];
    uint32_t u = (uint32_t)(key >> 32);
    uint32_t fi = ~((uint32_t)key);
    float score = funsort(u);
    uint32_t c = fi % NCLS;
    uint32_t sp = (fi / NCLS) & (HWD - 1);
    float xs = (float)(sp & (WD - 1));
    float ys = (float)(sp >> 7);
    const float* gp = in + ((size_t)b * NCH + NCLS) * HWD + sp;
    float g0 = gp[0], g1 = gp[HWD], g2 = gp[2 * HWD], g3 = gp[3 * HWD];
    float* o = out + ((size_t)b * MAXDET + t) * 8;
    o[0] = (float)(c + 1);
    o[1] = score;
    o[2] = (4.0f * xs - g0) * (1.0f / 512.0f);
    o[3] = (4.0f * ys - g1) * (1.0f / 512.0f);
    o[4] = (4.0f * xs + g2) * (1.0f / 512.0f);
    o[5] = (4.0f * ys + g3) * (1.0f / 512.0f);
    o[6] = ys;
    o[7] = xs;
  }
}

extern "C" void kernel_launch(void* const* d_in, const int* in_sizes, int n_in,
                              void* d_out, int out_size, void* d_ws, size_t ws_size,
                              hipStream_t stream) {
  (void)in_sizes; (void)n_in; (void)out_size; (void)ws_size;
  const float* in = (const float*)d_in[0];
  float* out = (float*)d_out;
  uint8_t* ws = (uint8_t*)d_ws;

  uint32_t* cnt    = (uint32_t*)(ws + CNT_OFF);
  uint32_t* done   = (uint32_t*)(ws + DONE_OFF);
  uint64_t* cand   = (uint64_t*)(ws + CAND_OFF);
  uint32_t* fbhist = (uint32_t*)(ws + FBHIST_OFF);
  uint64_t* fbkeys = (uint64_t*)(ws + FBKEYS_OFF);

  hipMemsetAsync(ws + DONE_OFF, 0, 8192, stream);  // zero done counters
  k_fused<<<dim3(NBLK, NBATCH), 256, 0, stream>>>(in, cand, cnt, done,
                                                  fbhist, fbkeys, out);
}

// Round 10
// 48.167 us; speedup vs baseline: 11.8375x; 11.8375x over previous
//
#include <hip/hip_runtime.h>
#include <stdint.h>

// CenterNet postprocess: y_pred (32, 84, 128, 128) f32 -> (32, 100, 8) f32
//
// Round-10: revert to round-6 structure (round-9's fused kernel regressed
// 13x: per-block device-scope __threadfence() = globally-serialized L2
// writeback/invalidate on gfx950 -> NEVER fence per-block in the hot path).
// Micro-opt: finalize gather flattened to coalesced (block,slot) loop.
//
//   k_pass1 : grid (160,32) x 256 thr; each block screens 8192 contiguous
//             floats (8 float4/thread); v >= 3.6 max4 guard; rare hits
//             (~208/batch) 3x3-NMS-tested via cached re-reads; private
//             32-slot cand region per block; count stored unconditionally
//             (no memset, no global atomics, no fences).
//   k_finalize (256 thr, 1 block/batch): prefix-sum 160 block counts,
//             coalesced gather, bitonic-sort (value,~index) keys, emit
//             top-100 in exact lax.top_k order. Any block overflow or total
//             outside [100,4096] -> exact in-block histogram fallback
//             (never taken on bench data; correct for arbitrary inputs).

#define NCLS   80
#define NCH    84
#define WD     128
#define HD     128
#define HWD    16384
#define NPB    (NCLS * HWD)     // 1310720 heatmap elements per batch
#define NBINS  4096
#define SKCAP  4096
#define MAXDET 100
#define NBATCH 32
#define STHR   3.6f             // static screen threshold (true p100 ~ 3.79)
#define NBLK   160              // pass1 blocks per batch
#define SLOT   32               // candidate slots per pass1 block

// ws layout (bytes):
#define CNT_OFF  0              // 32*160*4 = 20480 (pad to 32768)
#define CAND_OFF 32768          // 32*160*32*8 = 1310720

__device__ __forceinline__ uint32_t fsort(float f) {
  uint32_t u = __float_as_uint(f);
  return u ^ ((u & 0x80000000u) ? 0xFFFFFFFFu : 0x80000000u);
}
__device__ __forceinline__ float funsort(uint32_t u) {
  uint32_t b = (u & 0x80000000u) ? (u ^ 0x80000000u) : ~u;
  return __uint_as_float(b);
}

// exact 3x3 NMS max-of-neighbors for heatmap element e (within one batch)
__device__ __forceinline__ float nms_nbmax(const float* __restrict__ hmb, int e,
                                           float v) {
  int sp = e & (HWD - 1);
  int h = sp >> 7, w = sp & (WD - 1);
  const float* p = hmb + e;
  float m = v;
  bool wl = (w > 0), wr = (w < WD - 1);
  if (wl) m = fmaxf(m, p[-1]);
  if (wr) m = fmaxf(m, p[1]);
  if (h > 0) {
    m = fmaxf(m, p[-WD]);
    if (wl) m = fmaxf(m, p[-WD - 1]);
    if (wr) m = fmaxf(m, p[-WD + 1]);
  }
  if (h < HD - 1) {
    m = fmaxf(m, p[WD]);
    if (wl) m = fmaxf(m, p[WD - 1]);
    if (wr) m = fmaxf(m, p[WD + 1]);
  }
  return m;
}

__device__ __forceinline__ uint64_t make_key(uint32_t u, int e) {
  int sp = e & (HWD - 1);
  uint32_t fi = (uint32_t)(sp * NCLS + (e >> 14));  // (H,W,C) flat index
  return ((uint64_t)u << 32) | (uint32_t)(~fi);
}

// ---------------- pass 1: streaming screen, private-slot collect ------------
// grid (160, 32) x 256 threads; each block screens 8192 contiguous floats.
extern "C" __global__ __launch_bounds__(256)
void k_pass1(const float* __restrict__ in, uint64_t* __restrict__ cand,
             uint32_t* __restrict__ cnt) {
  __shared__ uint32_t lcnt;
  __shared__ uint64_t lbuf[SLOT];
  if (threadIdx.x == 0) lcnt = 0;
  __syncthreads();

  const int b = blockIdx.y;
  const int blk = blockIdx.x;
  const float* hmb = in + (size_t)b * NCH * HWD;
  const int base = blk * 8192 + (int)threadIdx.x * 4;

  float4 v[8];
#pragma unroll
  for (int it = 0; it < 8; ++it)
    v[it] = *reinterpret_cast<const float4*>(hmb + base + it * 1024);

#pragma unroll
  for (int it = 0; it < 8; ++it) {
    float4 w = v[it];
    float m4 = fmaxf(fmaxf(w.x, w.y), fmaxf(w.z, w.w));
    if (m4 >= STHR) {  // rare: one branch guards the detailed checks
      int r = base + it * 1024;
#define TRY(vi, off)                                                     \
      if (vi >= STHR && vi == nms_nbmax(hmb, r + off, vi)) {             \
        uint32_t pos = atomicAdd(&lcnt, 1u);                             \
        if (pos < SLOT) lbuf[pos] = make_key(fsort(vi), r + off);        \
      }
      TRY(w.x, 0) TRY(w.y, 1) TRY(w.z, 2) TRY(w.w, 3)
#undef TRY
    }
  }
  __syncthreads();

  uint32_t n = lcnt;
  uint64_t* cb = cand + ((size_t)b * NBLK + blk) * SLOT;
  uint32_t nn = (n < SLOT) ? n : SLOT;
  for (uint32_t i = threadIdx.x; i < nn; i += 256) cb[i] = lbuf[i];
  // raw count (may exceed SLOT -> finalize takes exact fallback)
  if (threadIdx.x == 0) cnt[(size_t)b * NBLK + blk] = n;
}

// ---------------- finalize: gather (+exact fallback) + sort + emit ----------
extern "C" __global__ __launch_bounds__(256)
void k_finalize(const float* __restrict__ in, const uint64_t* __restrict__ cand,
                const uint32_t* __restrict__ cnt, float* __restrict__ out) {
  const int b = blockIdx.x;
  const int t = threadIdx.x;
  const float* hmb = in + (size_t)b * NCH * HWD;

  __shared__ uint64_t sk[SKCAP];       // 32 KB
  __shared__ uint32_t hist[NBINS];     // 16 KB (fallback only)
  __shared__ uint32_t pfx[NBLK + 1];   // block-count prefix sums
  __shared__ uint32_t scnB[256];       // fallback bin scan
  __shared__ uint32_t flags, sthr_s, lcnt;

  if (t == 0) { flags = 0; sthr_s = 0; lcnt = 0; }
  __syncthreads();

  if (t < NBLK) {
    uint32_t c = cnt[(size_t)b * NBLK + t];
    if (c > SLOT) atomicOr(&flags, 1u);
    pfx[t] = c;
  }
  __syncthreads();
  if (t == 0) {
    uint32_t acc = 0;
    for (int i = 0; i < NBLK; ++i) { uint32_t u = pfx[i]; pfx[i] = acc; acc += u; }
    pfx[NBLK] = acc;
  }
  __syncthreads();

  uint32_t n = pfx[NBLK];
  bool fb = (flags != 0) || (n < MAXDET) || (n > SKCAP);

  if (!fb) {
    // coalesced gather: one (block, slot) pair per iteration-lane
    const uint64_t* cb = cand + (size_t)b * NBLK * SLOT;
    for (int idx = t; idx < NBLK * SLOT; idx += 256) {
      int i = idx >> 5;            // block
      int j = idx & (SLOT - 1);    // slot
      uint32_t off = pfx[i], ci = pfx[i + 1] - off;
      if ((uint32_t)j < ci) sk[off + j] = cb[idx];
    }
  } else {
    // ---- exact in-block fallback (arbitrary inputs; never taken on bench) --
    for (int i = t; i < NBINS; i += 256) hist[i] = 0;
    __syncthreads();
    uint32_t zp = 0, zn = 0;
    for (int e = t; e < NPB; e += 256) {
      float v = hmb[e];
      if (v == nms_nbmax(hmb, e, v)) {
        atomicAdd(&hist[fsort(v) >> 20], 1u);
      } else if (__float_as_uint(v) >> 31) zn++; else zp++;
    }
    for (int off = 32; off; off >>= 1) {
      zp += __shfl_down(zp, off);
      zn += __shfl_down(zn, off);
    }
    if ((t & 63) == 0) {
      if (zp) atomicAdd(&hist[2048], zp);  // suppressed +0.0
      if (zn) atomicAdd(&hist[2047], zn);  // suppressed -0.0
    }
    __syncthreads();
    uint32_t loc[16], own = 0;
#pragma unroll
    for (int i = 0; i < 16; ++i) { loc[i] = hist[t * 16 + i]; own += loc[i]; }
    scnB[t] = own;
    __syncthreads();
    if (t == 0) {
      uint32_t acc = 0;
      for (int j = 255; j >= 0; --j) { uint32_t v = scnB[j]; scnB[j] = acc; acc += v; }
    }
    __syncthreads();
    uint32_t above = scnB[t];
    if (above < MAXDET && above + own >= MAXDET) {
      uint32_t cum = above;
      for (int i = 15; i >= 0; --i) {
        cum += loc[i];
        if (cum >= MAXDET) { sthr_s = (uint32_t)(t * 16 + i); break; }
      }
    }
    __syncthreads();
    uint32_t uthr = sthr_s << 20;
    for (int e = t; e < NPB; e += 256) {
      float v = hmb[e];
      bool kept = (v == nms_nbmax(hmb, e, v));
      float nv = kept ? v : 0.0f * v;
      uint32_t u = fsort(nv);
      if (u >= uthr) {
        uint32_t pos = atomicAdd(&lcnt, 1u);
        if (pos < SKCAP) sk[pos] = make_key(u, e);
      }
    }
    __syncthreads();
    n = lcnt; if (n > SKCAP) n = SKCAP;
  }
  __syncthreads();

  uint32_t m = 128; while (m < n) m <<= 1;
  for (uint32_t i = t; i < m; i += 256) if (i >= n) sk[i] = 0ull;
  __syncthreads();

  // bitonic sort descending by (value, ~fi): value desc, index asc on ties
  for (uint32_t k = 2; k <= m; k <<= 1) {
    for (uint32_t j = k >> 1; j > 0; j >>= 1) {
      for (uint32_t i = t; i < m; i += 256) {
        uint32_t ixj = i ^ j;
        if (ixj > i && ixj < m) {
          uint64_t a = sk[i], c = sk[ixj];
          bool desc = (i & k) == 0;
          if (desc ? (a < c) : (a > c)) { sk[i] = c; sk[ixj] = a; }
        }
      }
      __syncthreads();
    }
  }

  if (t < MAXDET) {
    uint64_t key = sk[t];
    uint32_t u = (uint32_t)(key >> 32);
    uint32_t fi = ~((uint32_t)key);
    float score = funsort(u);
    uint32_t c = fi % NCLS;
    uint32_t sp = (fi / NCLS) & (HWD - 1);
    float xs = (float)(sp & (WD - 1));
    float ys = (float)(sp >> 7);
    const float* gp = in + ((size_t)b * NCH + NCLS) * HWD + sp;
    float g0 = gp[0], g1 = gp[HWD], g2 = gp[2 * HWD], g3 = gp[3 * HWD];
    float* o = out + ((size_t)b * MAXDET + t) * 8;
    o[0] = (float)(c + 1);
    o[1] = score;
    o[2] = (4.0f * xs - g0) * (1.0f / 512.0f);
    o[3] = (4.0f * ys - g1) * (1.0f / 512.0f);
    o[4] = (4.0f * xs + g2) * (1.0f / 512.0f);
    o[5] = (4.0f * ys + g3) * (1.0f / 512.0f);
    o[6] = ys;
    o[7] = xs;
  }
}

extern "C" void kernel_launch(void* const* d_in, const int* in_sizes, int n_in,
                              void* d_out, int out_size, void* d_ws, size_t ws_size,
                              hipStream_t stream) {
  (void)in_sizes; (void)n_in; (void)out_size; (void)ws_size;
  const float* in = (const float*)d_in[0];
  float* out = (float*)d_out;
  uint8_t* ws = (uint8_t*)d_ws;

  uint32_t* cnt  = (uint32_t*)(ws + CNT_OFF);
  uint64_t* cand = (uint64_t*)(ws + CAND_OFF);

  k_pass1<<<dim3(NBLK, NBATCH), 256, 0, stream>>>(in, cand, cnt);
  k_finalize<<<NBATCH, 256, 0, stream>>>(in, cand, cnt, out);
}

// Round 11
// 43.312 us; speedup vs baseline: 13.1646x; 1.1121x over previous
//
#include <hip/hip_runtime.h>
#include <stdint.h>

// CenterNet postprocess: y_pred (32, 84, 128, 128) f32 -> (32, 100, 8) f32
//
// FINAL (round-6 proven structure, measured 43.05 us; round-10's gather tweak
// was noise-negative and is reverted here).
//
//   k_pass1 : grid (160,32) x 256 thr; each block screens 8192 contiguous
//             floats (8 float4/thread); v >= 3.6 max4 guard; rare hits
//             (~208/batch) 3x3-NMS-tested via cached re-reads; private
//             32-slot cand region per block; count stored unconditionally
//             (no memset, no global atomics, no fences).
//   k_finalize (256 thr, 1 block/batch): prefix-sum 160 block counts, gather,
//             bitonic-sort (value,~index) keys, emit top-100 in exact
//             lax.top_k order. Any block overflow or total outside [100,4096]
//             -> exact in-block histogram fallback (never taken on bench
//             data; keeps correctness for arbitrary inputs).
//
// Session lessons encoded here:
//  - same-address LDS atomics (histogram) serialize the DS pipe (r2: 325us)
//  - same-cache-line device atomicAdds serialize at the coherence point
//    (r3: 565us); one padded atomic per block is fine (r4)
//  - per-block __threadfence() = globally-serialized L2 writeback on gfx950
//    (r9: 795us); never fence in the hot path -> two dispatches, not one
//  - pass1 streaming plateaus at ~4.7 TB/s blended L3+HBM for this pattern:
//    grid rebalance (r7), nt loads (r8), prefetch pipelining all null.

#define NCLS   80
#define NCH    84
#define WD     128
#define HD     128
#define HWD    16384
#define NPB    (NCLS * HWD)     // 1310720 heatmap elements per batch
#define NBINS  4096
#define SKCAP  4096
#define MAXDET 100
#define NBATCH 32
#define STHR   3.6f             // static screen threshold (true p100 ~ 3.79)
#define NBLK   160              // pass1 blocks per batch
#define SLOT   32               // candidate slots per pass1 block

// ws layout (bytes):
#define CNT_OFF  0              // 32*160*4 = 20480 (pad to 32768)
#define CAND_OFF 32768          // 32*160*32*8 = 1310720

__device__ __forceinline__ uint32_t fsort(float f) {
  uint32_t u = __float_as_uint(f);
  return u ^ ((u & 0x80000000u) ? 0xFFFFFFFFu : 0x80000000u);
}
__device__ __forceinline__ float funsort(uint32_t u) {
  uint32_t b = (u & 0x80000000u) ? (u ^ 0x80000000u) : ~u;
  return __uint_as_float(b);
}

// exact 3x3 NMS max-of-neighbors for heatmap element e (within one batch)
__device__ __forceinline__ float nms_nbmax(const float* __restrict__ hmb, int e,
                                           float v) {
  int sp = e & (HWD - 1);
  int h = sp >> 7, w = sp & (WD - 1);
  const float* p = hmb + e;
  float m = v;
  bool wl = (w > 0), wr = (w < WD - 1);
  if (wl) m = fmaxf(m, p[-1]);
  if (wr) m = fmaxf(m, p[1]);
  if (h > 0) {
    m = fmaxf(m, p[-WD]);
    if (wl) m = fmaxf(m, p[-WD - 1]);
    if (wr) m = fmaxf(m, p[-WD + 1]);
  }
  if (h < HD - 1) {
    m = fmaxf(m, p[WD]);
    if (wl) m = fmaxf(m, p[WD - 1]);
    if (wr) m = fmaxf(m, p[WD + 1]);
  }
  return m;
}

__device__ __forceinline__ uint64_t make_key(uint32_t u, int e) {
  int sp = e & (HWD - 1);
  uint32_t fi = (uint32_t)(sp * NCLS + (e >> 14));  // (H,W,C) flat index
  return ((uint64_t)u << 32) | (uint32_t)(~fi);
}

// ---------------- pass 1: streaming screen, private-slot collect ------------
// grid (160, 32) x 256 threads; each block screens 8192 contiguous floats.
extern "C" __global__ __launch_bounds__(256)
void k_pass1(const float* __restrict__ in, uint64_t* __restrict__ cand,
             uint32_t* __restrict__ cnt) {
  __shared__ uint32_t lcnt;
  __shared__ uint64_t lbuf[SLOT];
  if (threadIdx.x == 0) lcnt = 0;
  __syncthreads();

  const int b = blockIdx.y;
  const int blk = blockIdx.x;
  const float* hmb = in + (size_t)b * NCH * HWD;
  const int base = blk * 8192 + (int)threadIdx.x * 4;

  float4 v[8];
#pragma unroll
  for (int it = 0; it < 8; ++it)
    v[it] = *reinterpret_cast<const float4*>(hmb + base + it * 1024);

#pragma unroll
  for (int it = 0; it < 8; ++it) {
    float4 w = v[it];
    float m4 = fmaxf(fmaxf(w.x, w.y), fmaxf(w.z, w.w));
    if (m4 >= STHR) {  // rare: one branch guards the detailed checks
      int r = base + it * 1024;
#define TRY(vi, off)                                                     \
      if (vi >= STHR && vi == nms_nbmax(hmb, r + off, vi)) {             \
        uint32_t pos = atomicAdd(&lcnt, 1u);                             \
        if (pos < SLOT) lbuf[pos] = make_key(fsort(vi), r + off);        \
      }
      TRY(w.x, 0) TRY(w.y, 1) TRY(w.z, 2) TRY(w.w, 3)
#undef TRY
    }
  }
  __syncthreads();

  uint32_t n = lcnt;
  uint64_t* cb = cand + ((size_t)b * NBLK + blk) * SLOT;
  uint32_t nn = (n < SLOT) ? n : SLOT;
  for (uint32_t i = threadIdx.x; i < nn; i += 256) cb[i] = lbuf[i];
  // raw count (may exceed SLOT -> finalize takes exact fallback)
  if (threadIdx.x == 0) cnt[(size_t)b * NBLK + blk] = n;
}

// ---------------- finalize: gather (+exact fallback) + sort + emit ----------
extern "C" __global__ __launch_bounds__(256)
void k_finalize(const float* __restrict__ in, const uint64_t* __restrict__ cand,
                const uint32_t* __restrict__ cnt, float* __restrict__ out) {
  const int b = blockIdx.x;
  const int t = threadIdx.x;
  const float* hmb = in + (size_t)b * NCH * HWD;

  __shared__ uint64_t sk[SKCAP];       // 32 KB
  __shared__ uint32_t hist[NBINS];     // 16 KB (fallback only)
  __shared__ uint32_t pfx[NBLK + 1];   // block-count prefix sums
  __shared__ uint32_t scnB[256];       // fallback bin scan
  __shared__ uint32_t flags, sthr_s, lcnt;

  if (t == 0) { flags = 0; sthr_s = 0; lcnt = 0; }
  __syncthreads();

  if (t < NBLK) {
    uint32_t c = cnt[(size_t)b * NBLK + t];
    if (c > SLOT) atomicOr(&flags, 1u);
    pfx[t] = c;
  }
  __syncthreads();
  if (t == 0) {
    uint32_t acc = 0;
    for (int i = 0; i < NBLK; ++i) { uint32_t u = pfx[i]; pfx[i] = acc; acc += u; }
    pfx[NBLK] = acc;
  }
  __syncthreads();

  uint32_t n = pfx[NBLK];
  bool fb = (flags != 0) || (n < MAXDET) || (n > SKCAP);

  if (!fb) {
    // gather per-block segments into contiguous sk[0..n)
    const uint64_t* cb = cand + (size_t)b * NBLK * SLOT;
    for (int i = t; i < NBLK; i += 256) {
      uint32_t off = pfx[i], ci = pfx[i + 1] - off;
      for (uint32_t j = 0; j < ci; ++j) sk[off + j] = cb[(size_t)i * SLOT + j];
    }
  } else {
    // ---- exact in-block fallback (arbitrary inputs; never taken on bench) --
    for (int i = t; i < NBINS; i += 256) hist[i] = 0;
    __syncthreads();
    uint32_t zp = 0, zn = 0;
    for (int e = t; e < NPB; e += 256) {
      float v = hmb[e];
      if (v == nms_nbmax(hmb, e, v)) {
        atomicAdd(&hist[fsort(v) >> 20], 1u);
      } else if (__float_as_uint(v) >> 31) zn++; else zp++;
    }
    for (int off = 32; off; off >>= 1) {
      zp += __shfl_down(zp, off);
      zn += __shfl_down(zn, off);
    }
    if ((t & 63) == 0) {
      if (zp) atomicAdd(&hist[2048], zp);  // suppressed +0.0
      if (zn) atomicAdd(&hist[2047], zn);  // suppressed -0.0
    }
    __syncthreads();
    uint32_t loc[16], own = 0;
#pragma unroll
    for (int i = 0; i < 16; ++i) { loc[i] = hist[t * 16 + i]; own += loc[i]; }
    scnB[t] = own;
    __syncthreads();
    if (t == 0) {
      uint32_t acc = 0;
      for (int j = 255; j >= 0; --j) { uint32_t v = scnB[j]; scnB[j] = acc; acc += v; }
    }
    __syncthreads();
    uint32_t above = scnB[t];
    if (above < MAXDET && above + own >= MAXDET) {
      uint32_t cum = above;
      for (int i = 15; i >= 0; --i) {
        cum += loc[i];
        if (cum >= MAXDET) { sthr_s = (uint32_t)(t * 16 + i); break; }
      }
    }
    __syncthreads();
    uint32_t uthr = sthr_s << 20;
    for (int e = t; e < NPB; e += 256) {
      float v = hmb[e];
      bool kept = (v == nms_nbmax(hmb, e, v));
      float nv = kept ? v : 0.0f * v;
      uint32_t u = fsort(nv);
      if (u >= uthr) {
        uint32_t pos = atomicAdd(&lcnt, 1u);
        if (pos < SKCAP) sk[pos] = make_key(u, e);
      }
    }
    __syncthreads();
    n = lcnt; if (n > SKCAP) n = SKCAP;
  }
  __syncthreads();

  uint32_t m = 128; while (m < n) m <<= 1;
  for (uint32_t i = t; i < m; i += 256) if (i >= n) sk[i] = 0ull;
  __syncthreads();

  // bitonic sort descending by (value, ~fi): value desc, index asc on ties
  for (uint32_t k = 2; k <= m; k <<= 1) {
    for (uint32_t j = k >> 1; j > 0; j >>= 1) {
      for (uint32_t i = t; i < m; i += 256) {
        uint32_t ixj = i ^ j;
        if (ixj > i && ixj < m) {
          uint64_t a = sk[i], c = sk[ixj];
          bool desc = (i & k) == 0;
          if (desc ? (a < c) : (a > c)) { sk[i] = c; sk[ixj] = a; }
        }
      }
      __syncthreads();
    }
  }

  if (t < MAXDET) {
    uint64_t key = sk[t];
    uint32_t u = (uint32_t)(key >> 32);
    uint32_t fi = ~((uint32_t)key);
    float score = funsort(u);
    uint32_t c = fi % NCLS;
    uint32_t sp = (fi / NCLS) & (HWD - 1);
    float xs = (float)(sp & (WD - 1));
    float ys = (float)(sp >> 7);
    const float* gp = in + ((size_t)b * NCH + NCLS) * HWD + sp;
    float g0 = gp[0], g1 = gp[HWD], g2 = gp[2 * HWD], g3 = gp[3 * HWD];
    float* o = out + ((size_t)b * MAXDET + t) * 8;
    o[0] = (float)(c + 1);
    o[1] = score;
    o[2] = (4.0f * xs - g0) * (1.0f / 512.0f);
    o[3] = (4.0f * ys - g1) * (1.0f / 512.0f);
    o[4] = (4.0f * xs + g2) * (1.0f / 512.0f);
    o[5] = (4.0f * ys + g3) * (1.0f / 512.0f);
    o[6] = ys;
    o[7] = xs;
  }
}

extern "C" void kernel_launch(void* const* d_in, const int* in_sizes, int n_in,
                              void* d_out, int out_size, void* d_ws, size_t ws_size,
                              hipStream_t stream) {
  (void)in_sizes; (void)n_in; (void)out_size; (void)ws_size;
  const float* in = (const float*)d_in[0];
  float* out = (float*)d_out;
  uint8_t* ws = (uint8_t*)d_ws;

  uint32_t* cnt  = (uint32_t*)(ws + CNT_OFF);
  uint64_t* cand = (uint64_t*)(ws + CAND_OFF);

  k_pass1<<<dim3(NBLK, NBATCH), 256, 0, stream>>>(in, cand, cnt);
  k_finalize<<<NBATCH, 256, 0, stream>>>(in, cand, cnt, out);
}